// Round 3
// baseline (352.545 us; speedup 1.0000x reference)
//
#include <hip/hip_runtime.h>
#include <hip/hip_bf16.h>

#define D 64

__device__ __forceinline__ unsigned short f2bf(float x) {
    unsigned u = __float_as_uint(x);
    unsigned r = 0x7fffu + ((u >> 16) & 1u);   // round-to-nearest-even
    return (unsigned short)((u + r) >> 16);
}
__device__ __forceinline__ float bf2f(unsigned short b) {
    return __uint_as_float((unsigned)b << 16);
}

// ---------------- Kernel 1: per-node gate scalars + bf16 copy of h ----------------
// sd[n] = { h[n]·w_dst + gate_b, dnorm[n] },  ss[n] = { h[n]·w_src, dnorm[n] }
// 16 lanes/node, float4 loads. Optionally emits hb = bf16(h).
template<bool MAKE_BF16>
__global__ void fal_precompute(const float* __restrict__ h,
                               const float* __restrict__ dnorm,
                               const float* __restrict__ gate_w,
                               const float* __restrict__ gate_b,
                               float2* __restrict__ sd,
                               float2* __restrict__ ss,
                               unsigned short* __restrict__ hb,
                               int N) {
    int tid  = threadIdx.x;
    int lane = tid & 63;
    int wave = tid >> 6;
    int grp  = lane >> 4;
    int gl   = lane & 15;

    int node = blockIdx.x * 16 + wave * 4 + grp;
    int nc   = node < N ? node : N - 1;

    const float4* h4 = (const float4*)h;
    const float4* w4 = (const float4*)gate_w;

    float4 hv  = h4[nc * 16 + gl];
    float4 wd  = w4[gl];
    float4 wsr = w4[16 + gl];

    if (MAKE_BF16 && node < N) {
        ushort4 p = make_ushort4(f2bf(hv.x), f2bf(hv.y), f2bf(hv.z), f2bf(hv.w));
        *(ushort4*)&hb[(size_t)node * D + gl * 4] = p;
    }

    float a = hv.x * wd.x + hv.y * wd.y + hv.z * wd.z + hv.w * wd.w;
    float b = hv.x * wsr.x + hv.y * wsr.y + hv.z * wsr.z + hv.w * wsr.w;

    for (int off = 1; off < 16; off <<= 1) {
        a += __shfl_xor(a, off, 64);
        b += __shfl_xor(b, off, 64);
    }

    if (gl == 0 && node < N) {
        float dn = dnorm[node];
        sd[node] = make_float2(a + gate_b[0], dn);
        ss[node] = make_float2(b, dn);
    }
}

// ---------------- Kernel 2: dst histogram (4 edges/thread) ----------------
__global__ void fal_histogram(const int* __restrict__ dst,
                              int* __restrict__ deg, int E) {
    int t  = blockIdx.x * blockDim.x + threadIdx.x;
    int e0 = t * 4;
    if (e0 >= E) return;
    if (e0 + 3 < E) {
        int4 d4 = ((const int4*)dst)[t];
        atomicAdd(&deg[d4.x], 1);
        atomicAdd(&deg[d4.y], 1);
        atomicAdd(&deg[d4.z], 1);
        atomicAdd(&deg[d4.w], 1);
    } else {
        for (int e = e0; e < E; ++e) atomicAdd(&deg[dst[e]], 1);
    }
}

// ---------------- Kernel 3: order-free region assignment ----------------
__global__ void fal_assign(const int* __restrict__ deg,
                           int* __restrict__ start,
                           int* __restrict__ cursor,
                           int* __restrict__ total, int N) {
    int tid  = blockIdx.x * blockDim.x + threadIdx.x;
    int lane = threadIdx.x & 63;

    int d = (tid < N) ? deg[tid] : 0;

    int v = d;
    for (int off = 1; off < 64; off <<= 1) {
        int t = __shfl_up(v, off, 64);
        if (lane >= off) v += t;
    }
    int wave_total = __shfl(v, 63, 64);

    int base = 0;
    if (lane == 63) base = atomicAdd(total, wave_total);
    base = __shfl(base, 63, 64);

    int st = base + v - d;
    if (tid < N) {
        start[tid]  = st;
        cursor[tid] = st;
    }
}

// ---------------- Kernel 4: scatter (4 edges/thread, NT stores) ----------------
__global__ void fal_scatter(const int* __restrict__ src,
                            const int* __restrict__ dst,
                            const float2* __restrict__ sd,
                            const float2* __restrict__ ss,
                            int* __restrict__ cursor,
                            int2* __restrict__ perm, int E) {
    int t  = blockIdx.x * blockDim.x + threadIdx.x;
    int e0 = t * 4;
    if (e0 >= E) return;

    if (e0 + 3 < E) {
        int4 s4 = ((const int4*)src)[t];
        int4 d4 = ((const int4*)dst)[t];
        int sa[4] = {s4.x, s4.y, s4.z, s4.w};
        int da[4] = {d4.x, d4.y, d4.z, d4.w};
        float esc[4];
        #pragma unroll
        for (int j = 0; j < 4; ++j) {
            float2 ad = sd[da[j]];
            float2 bs = ss[sa[j]];
            float g = tanhf(ad.x + bs.x);
            esc[j] = g * ad.y * bs.y;
        }
        #pragma unroll
        for (int j = 0; j < 4; ++j) {
            int pos = atomicAdd(&cursor[da[j]], 1);
            long long v = ((long long)(unsigned long long)(unsigned)__float_as_uint(esc[j]) << 32)
                          | (unsigned)sa[j];
            __builtin_nontemporal_store(v, (long long*)&perm[pos]);
        }
    } else {
        for (int e = e0; e < E; ++e) {
            int s = src[e], dd = dst[e];
            float2 ad = sd[dd];
            float2 bs = ss[s];
            float g = tanhf(ad.x + bs.x);
            float esc = g * ad.y * bs.y;
            int pos = atomicAdd(&cursor[dd], 1);
            long long v = ((long long)(unsigned long long)(unsigned)__float_as_uint(esc) << 32)
                          | (unsigned)s;
            __builtin_nontemporal_store(v, (long long*)&perm[pos]);
        }
    }
}

// ---------------- Kernel 5: per-node accumulation ----------------
// One wave per dst node; lane = dim. bf16 gather when available.
template<bool BF16>
__global__ void fal_accumulate(const float* __restrict__ h,
                               const unsigned short* __restrict__ hb,
                               const int* __restrict__ start,
                               const int* __restrict__ deg,
                               const int2* __restrict__ perm,
                               float* __restrict__ z, int N) {
    int wave = (int)((blockIdx.x * blockDim.x + threadIdx.x) >> 6);
    int lane = threadIdx.x & 63;
    if (wave >= N) return;

    int rs = start[wave];
    int re = rs + deg[wave];

    float acc = 0.0f;
    for (int k0 = rs; k0 < re; k0 += 64) {
        int cnt = min(64, re - k0);
        long long pv = 0;
        if (k0 + lane < re)
            pv = __builtin_nontemporal_load((const long long*)&perm[k0 + lane]);
        int   ms = (int)(unsigned)(pv & 0xffffffffu);
        float me = __uint_as_float((unsigned)((unsigned long long)pv >> 32));

        int j = 0;
        for (; j + 4 <= cnt; j += 4) {
            int   s0 = __shfl(ms, j,     64), s1 = __shfl(ms, j + 1, 64);
            int   s2 = __shfl(ms, j + 2, 64), s3 = __shfl(ms, j + 3, 64);
            float e0 = __shfl(me, j,     64), e1 = __shfl(me, j + 1, 64);
            float e2 = __shfl(me, j + 2, 64), e3 = __shfl(me, j + 3, 64);
            float v0, v1, v2, v3;
            if (BF16) {
                v0 = bf2f(hb[(size_t)s0 * D + lane]);
                v1 = bf2f(hb[(size_t)s1 * D + lane]);
                v2 = bf2f(hb[(size_t)s2 * D + lane]);
                v3 = bf2f(hb[(size_t)s3 * D + lane]);
            } else {
                v0 = h[(size_t)s0 * D + lane];
                v1 = h[(size_t)s1 * D + lane];
                v2 = h[(size_t)s2 * D + lane];
                v3 = h[(size_t)s3 * D + lane];
            }
            acc = fmaf(v0, e0, acc);
            acc = fmaf(v1, e1, acc);
            acc = fmaf(v2, e2, acc);
            acc = fmaf(v3, e3, acc);
        }
        for (; j < cnt; ++j) {
            int   sj = __shfl(ms, j, 64);
            float ej = __shfl(me, j, 64);
            float v = BF16 ? bf2f(hb[(size_t)sj * D + lane]) : h[(size_t)sj * D + lane];
            acc = fmaf(v, ej, acc);
        }
    }
    z[(size_t)wave * D + lane] = acc;
}

extern "C" void kernel_launch(void* const* d_in, const int* in_sizes, int n_in,
                              void* d_out, int out_size, void* d_ws, size_t ws_size,
                              hipStream_t stream) {
    const float* h      = (const float*)d_in[0];
    const float* dnorm  = (const float*)d_in[1];
    const float* gate_w = (const float*)d_in[2];
    const float* gate_b = (const float*)d_in[3];
    const int*   src    = (const int*)d_in[4];
    const int*   dst    = (const int*)d_in[5];
    float*       z      = (float*)d_out;

    int N = in_sizes[1];   // 100000
    int E = in_sizes[4];   // 1600000

    // ---- workspace layout ----
    char* ws0 = (char*)d_ws;
    char* ws  = ws0;
    float2* sd     = (float2*)ws;  ws += (size_t)N * sizeof(float2);
    float2* ss     = (float2*)ws;  ws += (size_t)N * sizeof(float2);
    int*    deg    = (int*)ws;     ws += (size_t)N * sizeof(int);
    int*    total  = (int*)ws;     ws += 16;
    int*    start  = (int*)ws;     ws += (size_t)N * sizeof(int);
    int*    cursor = (int*)ws;     ws += (size_t)N * sizeof(int);
    int2*   perm   = (int2*)ws;    ws += (size_t)E * sizeof(int2);
    unsigned short* hb = (unsigned short*)ws;
    size_t need_with_hb = (size_t)(ws - ws0) + (size_t)N * D * sizeof(unsigned short);
    bool use_bf16 = (ws_size >= need_with_hb);

    hipMemsetAsync(deg, 0, (size_t)N * sizeof(int) + 16, stream);

    if (use_bf16)
        fal_precompute<true><<<(N + 15) / 16, 256, 0, stream>>>(h, dnorm, gate_w, gate_b, sd, ss, hb, N);
    else
        fal_precompute<false><<<(N + 15) / 16, 256, 0, stream>>>(h, dnorm, gate_w, gate_b, sd, ss, hb, N);

    int eq = (E + 3) / 4;
    fal_histogram<<<(eq + 255) / 256, 256, 0, stream>>>(dst, deg, E);

    fal_assign<<<(N + 255) / 256, 256, 0, stream>>>(deg, start, cursor, total, N);

    fal_scatter<<<(eq + 255) / 256, 256, 0, stream>>>(src, dst, sd, ss, cursor, perm, E);

    if (use_bf16)
        fal_accumulate<true><<<(N + 3) / 4, 256, 0, stream>>>(h, hb, start, deg, perm, z, N);
    else
        fal_accumulate<false><<<(N + 3) / 4, 256, 0, stream>>>(h, hb, start, deg, perm, z, N);
}